// Round 14
// baseline (577.698 us; speedup 1.0000x reference)
//
#include <hip/hip_runtime.h>
#include <stdint.h>

typedef __attribute__((ext_vector_type(8))) short s16x8;
typedef __attribute__((ext_vector_type(4))) float f32x4;

#define GLD_LDS16(gp, lp) __builtin_amdgcn_global_load_lds( \
    (__attribute__((address_space(1))) void*)(void*)(gp), \
    (__attribute__((address_space(3))) void*)(lp), 16, 0, 0)

__device__ __forceinline__ float b2f(unsigned short s) {
    unsigned int u = ((unsigned int)s) << 16;
    return __builtin_bit_cast(float, u);
}
__device__ __forceinline__ unsigned short f2b(float f) {
    unsigned int u = __builtin_bit_cast(unsigned int, f);
    u = (u + 0x7FFFu + ((u >> 16) & 1u)) >> 16;
    return (unsigned short)u;
}
__device__ __forceinline__ f32x4 mfma16(s16x8 a, s16x8 b, f32x4 c) {
    return __builtin_amdgcn_mfma_f32_16x16x32_bf16(a, b, c, 0, 0, 0);
}

// ---------------- RMSNorm (fp32 in -> bf16 out), D = 2048 ----------------
__global__ __launch_bounds__(256) void rmsnorm_bf16(
    const float* __restrict__ x, const float* __restrict__ wgt,
    unsigned short* __restrict__ out)
{
    const int row = blockIdx.x;
    const int t = threadIdx.x;
    const float* xr = x + (size_t)row * 2048;
    float4 a = *(const float4*)(xr + t * 8);
    float4 b = *(const float4*)(xr + t * 8 + 4);
    float ss = a.x*a.x + a.y*a.y + a.z*a.z + a.w*a.w
             + b.x*b.x + b.y*b.y + b.z*b.z + b.w*b.w;
    #pragma unroll
    for (int d = 1; d < 64; d <<= 1) ss += __shfl_xor(ss, d);
    __shared__ float red[4];
    if ((t & 63) == 0) red[t >> 6] = ss;
    __syncthreads();
    float tot = red[0] + red[1] + red[2] + red[3];
    float inv = rsqrtf(tot * (1.0f / 2048.0f) + 1e-5f);
    float vals[8] = {a.x, a.y, a.z, a.w, b.x, b.y, b.z, b.w};
    const float* wr_ = wgt + t * 8;
    s16x8 ov;
    #pragma unroll
    for (int j = 0; j < 8; ++j) ov[j] = (short)f2b(vals[j] * inv * wr_[j]);
    *(s16x8*)(out + (size_t)row * 2048 + t * 8) = ov;
}

// ------------- transpose + convert: in fp32 [K][N] -> out bf16 [N][K] -------------
__global__ __launch_bounds__(256) void transpose_to_bf16(
    const float* __restrict__ in, unsigned short* __restrict__ out, int K, int N)
{
    __shared__ float tile[64][65];
    const int n0 = blockIdx.x * 64, k0 = blockIdx.y * 64;
    const int t = threadIdx.x;
    const int kr = t >> 4, nc = (t & 15) * 4;
    #pragma unroll
    for (int i = 0; i < 4; ++i) {
        float4 v = *(const float4*)(in + (size_t)(k0 + kr + i * 16) * N + n0 + nc);
        tile[nc + 0][kr + i * 16] = v.x;
        tile[nc + 1][kr + i * 16] = v.y;
        tile[nc + 2][kr + i * 16] = v.z;
        tile[nc + 3][kr + i * 16] = v.w;
    }
    __syncthreads();
    const int nr = t >> 3, kc = (t & 7) * 8;
    #pragma unroll
    for (int p = 0; p < 2; ++p) {
        s16x8 o;
        #pragma unroll
        for (int j = 0; j < 8; ++j) o[j] = (short)f2b(tile[nr + p * 32][kc + j]);
        *(s16x8*)(out + (size_t)(n0 + nr + p * 32) * K + k0 + kc) = o;
    }
}

// ---------------- Minimal-sync GEMM (R10 schedule, BM/BN templated) ----------------
// C[4096,N] = A[4096,K] * B[N,K]^T. 8 waves (2M x 4N), per-wave (BM/2) x (BN/4).
// BM in {256,128}, BN in {256,128}. 4 straight-line phases/K-tile with setprio
// around each MFMA cluster, ONE vmcnt(0)+s_barrier per tile (R8-R10 verified).
// A LDS row order = [wr0-M0 | wr1-M0 | wr0-M1 | wr1-M1] quarters; chunk-XOR swizzle.
// EPI 0: C bf16.  EPI 1: C fp32 = acc+ADD.  EPI 2: C bf16 with fused RoPE.
template <int BM, int BN, int EPI>
__global__ __launch_bounds__(512, 2) void gemmq(
    const unsigned short* __restrict__ A,
    const unsigned short* __restrict__ B,
    void* __restrict__ Cv,
    const float* __restrict__ ADD,
    const float2* __restrict__ RT,
    int N, int K)
{
    constexpr int MT  = 4096 / BM;
    constexpr int MH  = BM / 2;        // per-wave rows
    constexpr int MQ  = BM / 4;        // rows per M-half per wave
    constexpr int MI  = BM / 64;       // A frags per M-half (4 or 2)
    constexpr int ALD = BM / 64;       // A stage units
    constexpr int WN  = BN / 4;
    constexpr int HN  = WN / 2;
    constexpr int NJQ = WN / 32;       // 2 (BN=256) or 1 (BN=128)
    constexpr int NBU = BN / 64;
    constexpr int ABUF = BM * 64;
    constexpr int BBUF = BN * 64;
    __shared__ __align__(16) unsigned short As[2 * ABUF];
    __shared__ __align__(16) unsigned short Bs[2 * BBUF];

    const int t = threadIdx.x;
    const int l = t & 63, w = t >> 6;
    const int l15 = l & 15, lg = l >> 4;
    const int wr = w >> 2, wc = w & 3;
    const int x7 = l15 & 7;
    const int cc0 = ((lg) ^ x7) << 3;
    const int cc1 = ((4 | lg) ^ x7) << 3;

    // bijective XCD-aware block swizzle (m204)
    const int nwg = (int)gridDim.x;
    const int orig = (int)blockIdx.x;
    const int q8 = nwg >> 3, r8 = nwg & 7;
    const int xcd = orig & 7, lid = orig >> 3;
    const int wg = (xcd < r8 ? xcd * (q8 + 1) : r8 * (q8 + 1) + (xcd - r8) * q8) + lid;
    const int m0 = (wg % MT) * BM;
    const int n0 = (wg / MT) * BN;

    const int tr = t >> 3;
    const int scol = ((t & 7) ^ (tr & 7)) << 3;
    const unsigned short* pA[ALD];
    #pragma unroll
    for (int u = 0; u < ALD; ++u) {
        const int lrow = u * 64 + tr;
        const int seg = lrow / MQ;
        const int g = (seg & 1) * MH + ((seg >> 1) & 1) * MQ + (lrow % MQ);
        pA[u] = A + (size_t)(m0 + g) * K + scol;
    }
    const unsigned short* pB[NBU];
    #pragma unroll
    for (int u = 0; u < NBU; ++u) {
        const int lrow = u * 64 + tr;
        const int h = lrow / (BN / 2), rem = lrow % (BN / 2);
        const int g = (rem / HN) * WN + h * HN + (rem % HN);
        pB[u] = B + (size_t)(n0 + g) * K + scol;
    }

    f32x4 acc[2][2][MI][NJQ] = {};
    s16x8 aF[MI][2];
    s16x8 bF[2][NJQ][2];

    const int NT = K / 64;

    #pragma unroll
    for (int u = 0; u < ALD; ++u) GLD_LDS16(pA[u], &As[u * 4096 + t * 8]);
    #pragma unroll
    for (int u = 0; u < NBU; ++u) GLD_LDS16(pB[u], &Bs[u * 4096 + t * 8]);
    asm volatile("s_waitcnt vmcnt(0)" ::: "memory");
    __builtin_amdgcn_s_barrier();

    for (int kt = 0; kt < NT; ++kt) {
        const int rb  = (kt & 1) ? ABUF : 0;
        const int rbB = (kt & 1) ? BBUF : 0;
        const int wb  = ABUF - rb;
        const int wbB = BBUF - rbB;
        const int knext = (kt + 1 < NT ? kt + 1 : kt) * 64;

        // ---- phase 1: (M0,N0); stage all A' ----
        #pragma unroll
        for (int i = 0; i < MI; ++i) {
            const int lr = wr * MQ + i * 16 + l15;
            aF[i][0] = *(const s16x8*)&As[rb + lr * 64 + cc0];
            aF[i][1] = *(const s16x8*)&As[rb + lr * 64 + cc1];
        }
        #pragma unroll
        for (int j = 0; j < NJQ; ++j) {
            const int lr = wc * HN + j * 16 + l15;
            bF[0][j][0] = *(const s16x8*)&Bs[rbB + lr * 64 + cc0];
            bF[0][j][1] = *(const s16x8*)&Bs[rbB + lr * 64 + cc1];
        }
        #pragma unroll
        for (int u = 0; u < ALD; ++u)
            GLD_LDS16(pA[u] + knext, &As[wb + u * 4096 + t * 8]);
        __builtin_amdgcn_s_setprio(1);
        #pragma unroll
        for (int kk = 0; kk < 2; ++kk)
            #pragma unroll
            for (int i = 0; i < MI; ++i)
                #pragma unroll
                for (int j = 0; j < NJQ; ++j)
                    acc[0][0][i][j] = mfma16(aF[i][kk], bF[0][j][kk], acc[0][0][i][j]);
        __builtin_amdgcn_s_setprio(0);

        // ---- phase 2: (M0,N1); stage all B' ----
        #pragma unroll
        for (int j = 0; j < NJQ; ++j) {
            const int lr = (BN / 2) + wc * HN + j * 16 + l15;
            bF[1][j][0] = *(const s16x8*)&Bs[rbB + lr * 64 + cc0];
            bF[1][j][1] = *(const s16x8*)&Bs[rbB + lr * 64 + cc1];
        }
        #pragma unroll
        for (int u = 0; u < NBU; ++u)
            GLD_LDS16(pB[u] + knext, &Bs[wbB + u * 4096 + t * 8]);
        __builtin_amdgcn_s_setprio(1);
        #pragma unroll
        for (int kk = 0; kk < 2; ++kk)
            #pragma unroll
            for (int i = 0; i < MI; ++i)
                #pragma unroll
                for (int j = 0; j < NJQ; ++j)
                    acc[0][1][i][j] = mfma16(aF[i][kk], bF[1][j][kk], acc[0][1][i][j]);
        __builtin_amdgcn_s_setprio(0);

        // ---- phase 3: (M1,N0) ----
        #pragma unroll
        for (int i = 0; i < MI; ++i) {
            const int lr = MH + wr * MQ + i * 16 + l15;
            aF[i][0] = *(const s16x8*)&As[rb + lr * 64 + cc0];
            aF[i][1] = *(const s16x8*)&As[rb + lr * 64 + cc1];
        }
        __builtin_amdgcn_s_setprio(1);
        #pragma unroll
        for (int kk = 0; kk < 2; ++kk)
            #pragma unroll
            for (int i = 0; i < MI; ++i)
                #pragma unroll
                for (int j = 0; j < NJQ; ++j)
                    acc[1][0][i][j] = mfma16(aF[i][kk], bF[0][j][kk], acc[1][0][i][j]);
        __builtin_amdgcn_s_setprio(0);

        // ---- phase 4: (M1,N1) ----
        __builtin_amdgcn_s_setprio(1);
        #pragma unroll
        for (int kk = 0; kk < 2; ++kk)
            #pragma unroll
            for (int i = 0; i < MI; ++i)
                #pragma unroll
                for (int j = 0; j < NJQ; ++j)
                    acc[1][1][i][j] = mfma16(aF[i][kk], bF[1][j][kk], acc[1][1][i][j]);
        __builtin_amdgcn_s_setprio(0);

        asm volatile("s_waitcnt vmcnt(0)" ::: "memory");
        __builtin_amdgcn_s_barrier();
    }

    if constexpr (EPI == 2) {
        unsigned short* Cb = (unsigned short*)Cv;
        const bool roped = (n0 < 2560);
        #pragma unroll
        for (int qm = 0; qm < 2; ++qm)
            #pragma unroll
            for (int i = 0; i < MI; ++i)
                #pragma unroll
                for (int r = 0; r < 4; ++r) {
                    const int row = m0 + wr * MH + qm * MQ + i * 16 + lg * 4 + r;
                    const size_t rbase = (size_t)row * N;
                    #pragma unroll
                    for (int j = 0; j < NJQ; ++j) {
                        const int d = j * 16 + l15;
                        const int c0 = n0 + wc * WN + j * 16 + l15;
                        float a = acc[qm][0][i][j][r];
                        float b = acc[qm][1][i][j][r];
                        if (roped) {
                            float2 cs = RT[row * 32 + d];
                            Cb[rbase + c0]      = f2b(a * cs.x - b * cs.y);
                            Cb[rbase + c0 + HN] = f2b(b * cs.x + a * cs.y);
                        } else {
                            Cb[rbase + c0]      = f2b(a);
                            Cb[rbase + c0 + HN] = f2b(b);
                        }
                    }
                }
    } else {
        #pragma unroll
        for (int qm = 0; qm < 2; ++qm)
            #pragma unroll
            for (int i = 0; i < MI; ++i)
                #pragma unroll
                for (int r = 0; r < 4; ++r) {
                    const int row = m0 + wr * MH + qm * MQ + i * 16 + lg * 4 + r;
                    const size_t rbase = (size_t)row * N;
                    #pragma unroll
                    for (int qn = 0; qn < 2; ++qn)
                        #pragma unroll
                        for (int j = 0; j < NJQ; ++j) {
                            const int col = n0 + wc * WN + qn * HN + j * 16 + l15;
                            float v = acc[qm][qn][i][j][r];
                            if constexpr (EPI == 0) {
                                ((unsigned short*)Cv)[rbase + col] = f2b(v);
                            } else {
                                ((float*)Cv)[rbase + col] = v + ADD[rbase + col];
                            }
                        }
                }
    }
}

// ---------------- Dual-B GLU GEMM (R10 verified, unchanged) ----------------
__global__ __launch_bounds__(512, 2) void gemm_glu(
    const unsigned short* __restrict__ A,
    const unsigned short* __restrict__ Bg,
    const unsigned short* __restrict__ By,
    unsigned short* __restrict__ act,
    int N, int K)
{
    constexpr int ABUF = 256 * 64, BBUF = 128 * 64;
    __shared__ __align__(16) unsigned short As[2 * ABUF];
    __shared__ __align__(16) unsigned short Bgs[2 * BBUF];
    __shared__ __align__(16) unsigned short Bys[2 * BBUF];

    const int t = threadIdx.x;
    const int l = t & 63, w = t >> 6;
    const int l15 = l & 15, lg = l >> 4;
    const int wr = w >> 2, wc = w & 3;
    const int x7 = l15 & 7;
    const int cc0 = ((lg) ^ x7) << 3;
    const int cc1 = ((4 | lg) ^ x7) << 3;

    const int nwg = (int)gridDim.x;
    const int orig = (int)blockIdx.x;
    const int q8 = nwg >> 3;
    const int xcd = orig & 7, lid = orig >> 3;
    const int wg = xcd * q8 + lid;
    const int m0 = (wg & 15) * 256;
    const int n0 = (wg >> 4) * 128;

    const int tr = t >> 3;
    const int scol = ((t & 7) ^ (tr & 7)) << 3;
    const unsigned short* pA[4];
    #pragma unroll
    for (int u = 0; u < 4; ++u) {
        const int lrow = u * 64 + tr;
        const int g = ((lrow >> 6) & 1) * 128 + (lrow >> 7) * 64 + (lrow & 63);
        pA[u] = A + (size_t)(m0 + g) * K + scol;
    }
    const unsigned short *pG[2], *pY[2];
    #pragma unroll
    for (int u = 0; u < 2; ++u) {
        const int g = (tr >> 4) * 32 + u * 16 + (tr & 15);
        pG[u] = Bg + (size_t)(n0 + g) * K + scol;
        pY[u] = By + (size_t)(n0 + g) * K + scol;
    }

    f32x4 accG[2][2][4] = {};
    f32x4 accY[2][2][4] = {};
    s16x8 aF[4][2];
    s16x8 gF[2][2], yF[2][2];

    const int NT = K / 64;

    #pragma unroll
    for (int u = 0; u < 4; ++u) GLD_LDS16(pA[u], &As[u * 4096 + t * 8]);
    GLD_LDS16(pG[0], &Bgs[0 * 4096 + t * 8]);
    GLD_LDS16(pY[0], &Bys[0 * 4096 + t * 8]);
    GLD_LDS16(pG[1], &Bgs[1 * 4096 + t * 8]);
    GLD_LDS16(pY[1], &Bys[1 * 4096 + t * 8]);
    asm volatile("s_waitcnt vmcnt(0)" ::: "memory");
    __builtin_amdgcn_s_barrier();

    for (int kt = 0; kt < NT; ++kt) {
        const int rb  = (kt & 1) ? ABUF : 0;
        const int rbB = (kt & 1) ? BBUF : 0;
        const int wb  = ABUF - rb;
        const int wbB = BBUF - rbB;
        const int knext = (kt + 1 < NT ? kt + 1 : kt) * 64;

        // ---- phase 1: (M0,GY0); stage all A' ----
        #pragma unroll
        for (int i = 0; i < 4; ++i) {
            const int lr = wr * 64 + i * 16 + l15;
            aF[i][0] = *(const s16x8*)&As[rb + lr * 64 + cc0];
            aF[i][1] = *(const s16x8*)&As[rb + lr * 64 + cc1];
        }
        {
            const int lr = wc * 16 + l15;
            gF[0][0] = *(const s16x8*)&Bgs[rbB + lr * 64 + cc0];
            gF[0][1] = *(const s16x8*)&Bgs[rbB + lr * 64 + cc1];
            yF[0][0] = *(const s16x8*)&Bys[rbB + lr * 64 + cc0];
            yF[0][1] = *(const s16x8*)&Bys[rbB + lr * 64 + cc1];
        }
        #pragma unroll
        for (int u = 0; u < 4; ++u)
            GLD_LDS16(pA[u] + knext, &As[wb + u * 4096 + t * 8]);
        __builtin_amdgcn_s_setprio(1);
        #pragma unroll
        for (int kk = 0; kk < 2; ++kk)
            #pragma unroll
            for (int i = 0; i < 4; ++i) {
                accG[0][0][i] = mfma16(aF[i][kk], gF[0][kk], accG[0][0][i]);
                accY[0][0][i] = mfma16(aF[i][kk], yF[0][kk], accY[0][0][i]);
            }
        __builtin_amdgcn_s_setprio(0);

        // ---- phase 2: (M0,GY1); stage all G',Y' ----
        {
            const int lr = 64 + wc * 16 + l15;
            gF[1][0] = *(const s16x8*)&Bgs[rbB + lr * 64 + cc0];
            gF[1][1] = *(const s16x8*)&Bgs[rbB + lr * 64 + cc1];
            yF[1][0] = *(const s16x8*)&Bys[rbB + lr * 64 + cc0];
            yF[1][1] = *(const s16x8*)&Bys[rbB + lr * 64 + cc1];
        }
        GLD_LDS16(pG[0] + knext, &Bgs[wbB + 0 * 4096 + t * 8]);
        GLD_LDS16(pY[0] + knext, &Bys[wbB + 0 * 4096 + t * 8]);
        GLD_LDS16(pG[1] + knext, &Bgs[wbB + 1 * 4096 + t * 8]);
        GLD_LDS16(pY[1] + knext, &Bys[wbB + 1 * 4096 + t * 8]);
        __builtin_amdgcn_s_setprio(1);
        #pragma unroll
        for (int kk = 0; kk < 2; ++kk)
            #pragma unroll
            for (int i = 0; i < 4; ++i) {
                accG[0][1][i] = mfma16(aF[i][kk], gF[1][kk], accG[0][1][i]);
                accY[0][1][i] = mfma16(aF[i][kk], yF[1][kk], accY[0][1][i]);
            }
        __builtin_amdgcn_s_setprio(0);

        // ---- phase 3: (M1,GY0) ----
        #pragma unroll
        for (int i = 0; i < 4; ++i) {
            const int lr = 128 + wr * 64 + i * 16 + l15;
            aF[i][0] = *(const s16x8*)&As[rb + lr * 64 + cc0];
            aF[i][1] = *(const s16x8*)&As[rb + lr * 64 + cc1];
        }
        __builtin_amdgcn_s_setprio(1);
        #pragma unroll
        for (int kk = 0; kk < 2; ++kk)
            #pragma unroll
            for (int i = 0; i < 4; ++i) {
                accG[1][0][i] = mfma16(aF[i][kk], gF[0][kk], accG[1][0][i]);
                accY[1][0][i] = mfma16(aF[i][kk], yF[0][kk], accY[1][0][i]);
            }
        __builtin_amdgcn_s_setprio(0);

        // ---- phase 4: (M1,GY1) ----
        __builtin_amdgcn_s_setprio(1);
        #pragma unroll
        for (int kk = 0; kk < 2; ++kk)
            #pragma unroll
            for (int i = 0; i < 4; ++i) {
                accG[1][1][i] = mfma16(aF[i][kk], gF[1][kk], accG[1][1][i]);
                accY[1][1][i] = mfma16(aF[i][kk], yF[1][kk], accY[1][1][i]);
            }
        __builtin_amdgcn_s_setprio(0);

        asm volatile("s_waitcnt vmcnt(0)" ::: "memory");
        __builtin_amdgcn_s_barrier();
    }

    #pragma unroll
    for (int qm = 0; qm < 2; ++qm)
        #pragma unroll
        for (int i = 0; i < 4; ++i)
            #pragma unroll
            for (int r = 0; r < 4; ++r) {
                const int row = m0 + wr * 128 + qm * 64 + i * 16 + lg * 4 + r;
                const size_t rbase = (size_t)row * N;
                #pragma unroll
                for (int qn = 0; qn < 2; ++qn) {
                    const int col = n0 + wc * 32 + qn * 16 + l15;
                    float g = accG[qm][qn][i][r];
                    float y = accY[qm][qn][i][r];
                    float sg = g / (1.0f + expf(-g));
                    act[rbase + col] = f2b(sg * y);
                }
            }
}

// ---------------- RoPE table: [S][32] of (cos, sin) ----------------
__global__ void rope_tab_k(float2* __restrict__ tab) {
    int i = blockIdx.x * 256 + threadIdx.x;
    if (i >= 4096 * 32) return;
    int s = i >> 5, d = i & 31;
    float inv = exp2f(-(float)d * (13.287712379549449f / 32.0f));
    float fr = (float)s * inv;
    float sv, cv;
    sincosf(fr, &sv, &cv);
    tab[i] = make_float2(cv, sv);
}

// ---------------- Sliding-window attention, mask-specialized tiles (R13) ----------------
__global__ __launch_bounds__(256) void attn_swa(
    const unsigned short* __restrict__ qkv,
    unsigned short* __restrict__ out)
{
    constexpr int LDQ = 3072;
    const int qb = blockIdx.x;
    const int h = blockIdx.y;
    const int kvh = h >> 2;
    const int q0 = qb * 64;
    const int t = threadIdx.x, l = t & 63, w = t >> 6;
    const int l15 = l & 15, lg = l >> 4;

    __shared__ unsigned short Kl[64 * 64];
    __shared__ unsigned short Vt[64 * 72];
    __shared__ unsigned short Pl[4 * 16 * 72];

    s16x8 qf[2];
    {
        const unsigned short* qp = qkv + (size_t)(q0 + w * 16 + l15) * LDQ + h * 64 + lg * 8;
        qf[0] = *(const s16x8*)(qp);
        qf[1] = *(const s16x8*)(qp + 32);
    }
    float m_run[4] = {-1e30f, -1e30f, -1e30f, -1e30f};
    float l_run[4] = {0.f, 0.f, 0.f, 0.f};
    f32x4 o[4] = {};

    const float SC = 0.0625f * 1.4426950408889634f;

    auto do_tile = [&](const int ks, const int mode) {
        __syncthreads();
        {
            const unsigned short* kg = qkv + (size_t)(ks + (t >> 3)) * LDQ + 2048 + kvh * 64 + (t & 7) * 8;
            GLD_LDS16(kg, Kl + t * 8);
            GLD_LDS16(kg + (size_t)32 * LDQ, Kl + t * 8 + 2048);
        }
        {
            const unsigned short* vg = qkv + (size_t)(ks + l) * LDQ + 2560 + kvh * 64 + w * 16;
            s16x8 v0 = *(const s16x8*)vg;
            s16x8 v1 = *(const s16x8*)(vg + 8);
            #pragma unroll
            for (int j = 0; j < 8; ++j) Vt[(w * 16 + j) * 72 + l] = (unsigned short)v0[j];
            #pragma unroll
            for (int j = 0; j < 8; ++j) Vt[(w * 16 + 8 + j) * 72 + l] = (unsigned short)v1[j];
        }
        __syncthreads();

        f32x4 sf[4] = {};
        #pragma unroll
        for (int kf = 0; kf < 4; ++kf) {
            #pragma unroll
            for (int kk = 0; kk < 2; ++kk) {
                s16x8 kb = *(const s16x8*)(Kl + (kf * 16 + l15) * 64 + kk * 32 + lg * 8);
                sf[kf] = mfma16(qf[kk], kb, sf[kf]);
            }
        }

        float tmax[4];
        #pragma unroll
        for (int r = 0; r < 4; ++r) {
            float mx;
            if (mode == 0) {
                mx = fmaxf(fmaxf(sf[0][r], sf[1][r]), fmaxf(sf[2][r], sf[3][r]));
            } else {
                const int qrow = q0 + w * 16 + lg * 4 + r;
                mx = -1e30f;
                #pragma unroll
                for (int kf = 0; kf < 4; ++kf) {
                    const int key = ks + kf * 16 + l15;
                    const bool valid = (mode == 1) ? (qrow - key < 512) : (key <= qrow);
                    if (valid) mx = fmaxf(mx, sf[kf][r]);
                }
            }
            #pragma unroll
            for (int d2 = 1; d2 < 16; d2 <<= 1) mx = fmaxf(mx, __shfl_xor(mx, d2));
            tmax[r] = mx;
        }

        float alpha[4], rsum[4];
        #pragma unroll
        for (int r = 0; r < 4; ++r) {
            float mnew = fmaxf(m_run[r], tmax[r]);
            alpha[r] = exp2f((m_run[r] - mnew) * SC);
            m_run[r] = mnew;
            rsum[r] = 0.f;
        }

        unsigned short* Pw = Pl + w * (16 * 72);
        #pragma unroll
        for (int kf = 0; kf < 4; ++kf) {
            #pragma unroll
            for (int r = 0; r < 4; ++r) {
                float p;
                if (mode == 0) {
                    p = exp2f((sf[kf][r] - m_run[r]) * SC);
                } else {
                    const int qrow = q0 + w * 16 + lg * 4 + r;
                    const int key = ks + kf * 16 + l15;
                    const bool valid = (mode == 1) ? (qrow - key < 512) : (key <= qrow);
                    p = valid ? exp2f((sf[kf][r] - m_run[r]) * SC) : 0.f;
                }
                rsum[r] += p;
                Pw[(lg * 4 + r) * 72 + kf * 16 + l15] = f2b(p);
            }
        }
        #pragma unroll
        for (int r = 0; r < 4; ++r) {
            #pragma unroll
            for (int d2 = 1; d2 < 16; d2 <<= 1) rsum[r] += __shfl_xor(rsum[r], d2);
            l_run[r] = l_run[r] * alpha[r] + rsum[r];
        }
        #pragma unroll
        for (int hf = 0; hf < 4; ++hf)
            #pragma unroll
            for (int r = 0; r < 4; ++r) o[hf][r] *= alpha[r];

        asm volatile("s_waitcnt lgkmcnt(0)" ::: "memory");
        __builtin_amdgcn_sched_barrier(0);

        #pragma unroll
        for (int kk2 = 0; kk2 < 2; ++kk2) {
            s16x8 pa = *(const s16x8*)(Pw + l15 * 72 + kk2 * 32 + lg * 8);
            #pragma unroll
            for (int hf = 0; hf < 4; ++hf) {
                s16x8 vb = *(const s16x8*)(Vt + (hf * 16 + l15) * 72 + kk2 * 32 + lg * 8);
                o[hf] = mfma16(pa, vb, o[hf]);
            }
        }
    };

    if (qb >= 8) {
        do_tile((qb - 8) * 64, 1);
        for (int kt = qb - 7; kt < qb; ++kt) do_tile(kt * 64, 0);
    } else {
        for (int kt = 0; kt < qb; ++kt) do_tile(kt * 64, 0);
    }
    do_tile(qb * 64, 2);

    #pragma unroll
    for (int r = 0; r < 4; ++r) {
        int qrow = q0 + w * 16 + lg * 4 + r;
        float invl = 1.0f / l_run[r];
        unsigned short* orow = out + (size_t)qrow * 2048 + h * 64;
        #pragma unroll
        for (int hf = 0; hf < 4; ++hf)
            orow[hf * 16 + l15] = f2b(o[hf][r] * invl);
    }
}

extern "C" void kernel_launch(void* const* d_in, const int* in_sizes, int n_in,
                              void* d_out, int out_size, void* d_ws, size_t ws_size,
                              hipStream_t stream)
{
    const float* hidden = (const float*)d_in[0];
    const float* w_mix  = (const float*)d_in[1];
    const float* wq     = (const float*)d_in[2];
    const float* wk     = (const float*)d_in[3];
    const float* wv     = (const float*)d_in[4];
    const float* wo     = (const float*)d_in[5];
    const float* w_mlp  = (const float*)d_in[6];
    const float* wg     = (const float*)d_in[7];
    const float* wd     = (const float*)d_in[8];
    float* out = (float*)d_out;

    char* ws = (char*)d_ws;
    size_t off = 0;
    auto alloc = [&](size_t bytes) {
        char* p = ws + off;
        off += (bytes + 255) & ~(size_t)255;
        return p;
    };
    unsigned short* Wt   = (unsigned short*)alloc((size_t)11264 * 2048 * 2);
    unsigned short* xn   = (unsigned short*)alloc((size_t)4096 * 2048 * 2);
    unsigned short* qkv  = (unsigned short*)alloc((size_t)4096 * 3072 * 2);
    float2*         rtab = (float2*)alloc((size_t)4096 * 32 * 8);
    unsigned short* attn = (unsigned short*)alloc((size_t)4096 * 2048 * 2);
    float*          hbuf = (float*)alloc((size_t)4096 * 2048 * 4);
    unsigned short* act  = (unsigned short*)alloc((size_t)4096 * 5632 * 2);

    // 0. RoPE table
    rope_tab_k<<<(4096 * 32 + 255) / 256, 256, 0, stream>>>(rtab);

    // 1. x = rmsnorm(hidden) -> bf16
    rmsnorm_bf16<<<4096, 256, 0, stream>>>(hidden, w_mix, xn);

    // 2. W^T for q,k,v concatenated
    transpose_to_bf16<<<dim3(32, 32), 256, 0, stream>>>(wq, Wt, 2048, 2048);
    transpose_to_bf16<<<dim3(8, 32), 256, 0, stream>>>(wk, Wt + (size_t)2048 * 2048, 2048, 512);
    transpose_to_bf16<<<dim3(8, 32), 256, 0, stream>>>(wv, Wt + (size_t)2560 * 2048, 2048, 512);

    // 3. qkv = x @ [wq|wk|wv] with fused RoPE   (N=3072) 256x256 -> 192 blocks
    gemmq<256, 256, 2><<<192, 512, 0, stream>>>(xn, Wt, qkv, nullptr, rtab, 3072, 2048);

    // 4. sliding-window attention
    attn_swa<<<dim3(64, 32), 256, 0, stream>>>(qkv, attn);

    // 5. h = hidden + attn @ wo   (N=2048) 128x256 -> 256 blocks
    transpose_to_bf16<<<dim3(32, 32), 256, 0, stream>>>(wo, Wt, 2048, 2048);
    gemmq<128, 256, 1><<<256, 512, 0, stream>>>(attn, Wt, hbuf, hidden, nullptr, 2048, 2048);

    // 6. xn2 = rmsnorm(h)
    rmsnorm_bf16<<<4096, 256, 0, stream>>>(hbuf, w_mlp, xn);

    // 7. MLP: act = silu(x@wg_gate^T) * (x@wg_y^T)  -- 704 blocks
    transpose_to_bf16<<<dim3(176, 32), 256, 0, stream>>>(wg, Wt, 2048, 11264);
    gemm_glu<<<704, 512, 0, stream>>>(xn, Wt, Wt + (size_t)5632 * 2048, act, 5632, 2048);

    // 8. out = h + act @ w_down   (N=2048, K=5632) 128x256 -> 256 blocks
    transpose_to_bf16<<<dim3(32, 88), 256, 0, stream>>>(wd, Wt, 5632, 2048);
    gemmq<128, 256, 1><<<256, 512, 0, stream>>>(act, Wt, out, hbuf, nullptr, 2048, 5632);
}

// Round 15
// 541.978 us; speedup vs baseline: 1.0659x; 1.0659x over previous
//
#include <hip/hip_runtime.h>
#include <stdint.h>

typedef __attribute__((ext_vector_type(8))) short s16x8;
typedef __attribute__((ext_vector_type(4))) float f32x4;

#define GLD_LDS16(gp, lp) __builtin_amdgcn_global_load_lds( \
    (__attribute__((address_space(1))) void*)(void*)(gp), \
    (__attribute__((address_space(3))) void*)(lp), 16, 0, 0)

__device__ __forceinline__ float b2f(unsigned short s) {
    unsigned int u = ((unsigned int)s) << 16;
    return __builtin_bit_cast(float, u);
}
__device__ __forceinline__ unsigned short f2b(float f) {
    unsigned int u = __builtin_bit_cast(unsigned int, f);
    u = (u + 0x7FFFu + ((u >> 16) & 1u)) >> 16;
    return (unsigned short)u;
}
__device__ __forceinline__ f32x4 mfma16(s16x8 a, s16x8 b, f32x4 c) {
    return __builtin_amdgcn_mfma_f32_16x16x32_bf16(a, b, c, 0, 0, 0);
}

// ---------------- RMSNorm (fp32 in -> bf16 out), D = 2048 ----------------
__global__ __launch_bounds__(256) void rmsnorm_bf16(
    const float* __restrict__ x, const float* __restrict__ wgt,
    unsigned short* __restrict__ out)
{
    const int row = blockIdx.x;
    const int t = threadIdx.x;
    const float* xr = x + (size_t)row * 2048;
    float4 a = *(const float4*)(xr + t * 8);
    float4 b = *(const float4*)(xr + t * 8 + 4);
    float ss = a.x*a.x + a.y*a.y + a.z*a.z + a.w*a.w
             + b.x*b.x + b.y*b.y + b.z*b.z + b.w*b.w;
    #pragma unroll
    for (int d = 1; d < 64; d <<= 1) ss += __shfl_xor(ss, d);
    __shared__ float red[4];
    if ((t & 63) == 0) red[t >> 6] = ss;
    __syncthreads();
    float tot = red[0] + red[1] + red[2] + red[3];
    float inv = rsqrtf(tot * (1.0f / 2048.0f) + 1e-5f);
    float vals[8] = {a.x, a.y, a.z, a.w, b.x, b.y, b.z, b.w};
    const float* wr_ = wgt + t * 8;
    s16x8 ov;
    #pragma unroll
    for (int j = 0; j < 8; ++j) ov[j] = (short)f2b(vals[j] * inv * wr_[j]);
    *(s16x8*)(out + (size_t)row * 2048 + t * 8) = ov;
}

// ------------- transpose + convert: in fp32 [K][N] -> out bf16 [N][K] -------------
__global__ __launch_bounds__(256) void transpose_to_bf16(
    const float* __restrict__ in, unsigned short* __restrict__ out, int K, int N)
{
    __shared__ float tile[64][65];
    const int n0 = blockIdx.x * 64, k0 = blockIdx.y * 64;
    const int t = threadIdx.x;
    const int kr = t >> 4, nc = (t & 15) * 4;
    #pragma unroll
    for (int i = 0; i < 4; ++i) {
        float4 v = *(const float4*)(in + (size_t)(k0 + kr + i * 16) * N + n0 + nc);
        tile[nc + 0][kr + i * 16] = v.x;
        tile[nc + 1][kr + i * 16] = v.y;
        tile[nc + 2][kr + i * 16] = v.z;
        tile[nc + 3][kr + i * 16] = v.w;
    }
    __syncthreads();
    const int nr = t >> 3, kc = (t & 7) * 8;
    #pragma unroll
    for (int p = 0; p < 2; ++p) {
        s16x8 o;
        #pragma unroll
        for (int j = 0; j < 8; ++j) o[j] = (short)f2b(tile[nr + p * 32][kc + j]);
        *(s16x8*)(out + (size_t)(n0 + nr + p * 32) * K + k0 + kc) = o;
    }
}

// ---------------- Minimal-sync GEMM (R10 verified: 48% MfmaUtil) ----------------
template <int BN, int EPI>
__global__ __launch_bounds__(512, 2) void gemmq(
    const unsigned short* __restrict__ A,
    const unsigned short* __restrict__ B,
    void* __restrict__ Cv,
    const float* __restrict__ ADD,
    const float2* __restrict__ RT,
    int N, int K)
{
    constexpr int WN  = BN / 4;
    constexpr int HN  = WN / 2;
    constexpr int NJQ = WN / 32;
    constexpr int NBU = BN / 64;
    constexpr int ABUF = 256 * 64;
    constexpr int BBUF = BN * 64;
    __shared__ __align__(16) unsigned short As[2 * ABUF];
    __shared__ __align__(16) unsigned short Bs[2 * BBUF];

    const int t = threadIdx.x;
    const int l = t & 63, w = t >> 6;
    const int l15 = l & 15, lg = l >> 4;
    const int wr = w >> 2, wc = w & 3;
    const int x7 = l15 & 7;
    const int cc0 = ((lg) ^ x7) << 3;
    const int cc1 = ((4 | lg) ^ x7) << 3;

    const int nwg = (int)gridDim.x;
    const int orig = (int)blockIdx.x;
    const int q8 = nwg >> 3, r8 = nwg & 7;
    const int xcd = orig & 7, lid = orig >> 3;
    const int wg = (xcd < r8 ? xcd * (q8 + 1) : r8 * (q8 + 1) + (xcd - r8) * q8) + lid;
    const int m0 = (wg & 15) * 256;
    const int n0 = (wg >> 4) * BN;

    const int tr = t >> 3;
    const int scol = ((t & 7) ^ (tr & 7)) << 3;
    const unsigned short* pA[4];
    #pragma unroll
    for (int u = 0; u < 4; ++u) {
        const int lrow = u * 64 + tr;
        const int g = ((lrow >> 6) & 1) * 128 + (lrow >> 7) * 64 + (lrow & 63);
        pA[u] = A + (size_t)(m0 + g) * K + scol;
    }
    const unsigned short* pB[NBU];
    #pragma unroll
    for (int u = 0; u < NBU; ++u) {
        const int lrow = u * 64 + tr;
        const int h = lrow / (BN / 2), rem = lrow % (BN / 2);
        const int g = (rem / HN) * WN + h * HN + (rem % HN);
        pB[u] = B + (size_t)(n0 + g) * K + scol;
    }

    f32x4 acc[2][2][4][NJQ] = {};
    s16x8 aF[4][2];
    s16x8 bF[2][NJQ][2];

    const int NT = K / 64;

    #pragma unroll
    for (int u = 0; u < 4; ++u) GLD_LDS16(pA[u], &As[u * 4096 + t * 8]);
    #pragma unroll
    for (int u = 0; u < NBU; ++u) GLD_LDS16(pB[u], &Bs[u * 4096 + t * 8]);
    asm volatile("s_waitcnt vmcnt(0)" ::: "memory");
    __builtin_amdgcn_s_barrier();

    for (int kt = 0; kt < NT; ++kt) {
        const int rb  = (kt & 1) ? ABUF : 0;
        const int rbB = (kt & 1) ? BBUF : 0;
        const int wb  = ABUF - rb;
        const int wbB = BBUF - rbB;
        const int knext = (kt + 1 < NT ? kt + 1 : kt) * 64;

        // ---- phase 1: (M0,N0); stage all A' ----
        #pragma unroll
        for (int i = 0; i < 4; ++i) {
            const int lr = wr * 64 + i * 16 + l15;
            aF[i][0] = *(const s16x8*)&As[rb + lr * 64 + cc0];
            aF[i][1] = *(const s16x8*)&As[rb + lr * 64 + cc1];
        }
        #pragma unroll
        for (int j = 0; j < NJQ; ++j) {
            const int lr = wc * HN + j * 16 + l15;
            bF[0][j][0] = *(const s16x8*)&Bs[rbB + lr * 64 + cc0];
            bF[0][j][1] = *(const s16x8*)&Bs[rbB + lr * 64 + cc1];
        }
        #pragma unroll
        for (int u = 0; u < 4; ++u)
            GLD_LDS16(pA[u] + knext, &As[wb + u * 4096 + t * 8]);
        __builtin_amdgcn_s_setprio(1);
        #pragma unroll
        for (int kk = 0; kk < 2; ++kk)
            #pragma unroll
            for (int i = 0; i < 4; ++i)
                #pragma unroll
                for (int j = 0; j < NJQ; ++j)
                    acc[0][0][i][j] = mfma16(aF[i][kk], bF[0][j][kk], acc[0][0][i][j]);
        __builtin_amdgcn_s_setprio(0);

        // ---- phase 2: (M0,N1); stage all B' ----
        #pragma unroll
        for (int j = 0; j < NJQ; ++j) {
            const int lr = (BN / 2) + wc * HN + j * 16 + l15;
            bF[1][j][0] = *(const s16x8*)&Bs[rbB + lr * 64 + cc0];
            bF[1][j][1] = *(const s16x8*)&Bs[rbB + lr * 64 + cc1];
        }
        #pragma unroll
        for (int u = 0; u < NBU; ++u)
            GLD_LDS16(pB[u] + knext, &Bs[wbB + u * 4096 + t * 8]);
        __builtin_amdgcn_s_setprio(1);
        #pragma unroll
        for (int kk = 0; kk < 2; ++kk)
            #pragma unroll
            for (int i = 0; i < 4; ++i)
                #pragma unroll
                for (int j = 0; j < NJQ; ++j)
                    acc[0][1][i][j] = mfma16(aF[i][kk], bF[1][j][kk], acc[0][1][i][j]);
        __builtin_amdgcn_s_setprio(0);

        // ---- phase 3: (M1,N0) ----
        #pragma unroll
        for (int i = 0; i < 4; ++i) {
            const int lr = 128 + wr * 64 + i * 16 + l15;
            aF[i][0] = *(const s16x8*)&As[rb + lr * 64 + cc0];
            aF[i][1] = *(const s16x8*)&As[rb + lr * 64 + cc1];
        }
        __builtin_amdgcn_s_setprio(1);
        #pragma unroll
        for (int kk = 0; kk < 2; ++kk)
            #pragma unroll
            for (int i = 0; i < 4; ++i)
                #pragma unroll
                for (int j = 0; j < NJQ; ++j)
                    acc[1][0][i][j] = mfma16(aF[i][kk], bF[0][j][kk], acc[1][0][i][j]);
        __builtin_amdgcn_s_setprio(0);

        // ---- phase 4: (M1,N1) ----
        __builtin_amdgcn_s_setprio(1);
        #pragma unroll
        for (int kk = 0; kk < 2; ++kk)
            #pragma unroll
            for (int i = 0; i < 4; ++i)
                #pragma unroll
                for (int j = 0; j < NJQ; ++j)
                    acc[1][1][i][j] = mfma16(aF[i][kk], bF[1][j][kk], acc[1][1][i][j]);
        __builtin_amdgcn_s_setprio(0);

        asm volatile("s_waitcnt vmcnt(0)" ::: "memory");
        __builtin_amdgcn_s_barrier();
    }

    if constexpr (EPI == 2) {
        unsigned short* Cb = (unsigned short*)Cv;
        const bool roped = (n0 < 2560);
        #pragma unroll
        for (int qm = 0; qm < 2; ++qm)
            #pragma unroll
            for (int i = 0; i < 4; ++i)
                #pragma unroll
                for (int r = 0; r < 4; ++r) {
                    const int row = m0 + wr * 128 + qm * 64 + i * 16 + lg * 4 + r;
                    const size_t rbase = (size_t)row * N;
                    #pragma unroll
                    for (int j = 0; j < NJQ; ++j) {
                        const int d = j * 16 + l15;
                        const int c0 = n0 + wc * WN + j * 16 + l15;
                        float a = acc[qm][0][i][j][r];
                        float b = acc[qm][1][i][j][r];
                        if (roped) {
                            float2 cs = RT[row * 32 + d];
                            Cb[rbase + c0]      = f2b(a * cs.x - b * cs.y);
                            Cb[rbase + c0 + HN] = f2b(b * cs.x + a * cs.y);
                        } else {
                            Cb[rbase + c0]      = f2b(a);
                            Cb[rbase + c0 + HN] = f2b(b);
                        }
                    }
                }
    } else {
        #pragma unroll
        for (int qm = 0; qm < 2; ++qm)
            #pragma unroll
            for (int i = 0; i < 4; ++i)
                #pragma unroll
                for (int r = 0; r < 4; ++r) {
                    const int row = m0 + wr * 128 + qm * 64 + i * 16 + lg * 4 + r;
                    const size_t rbase = (size_t)row * N;
                    #pragma unroll
                    for (int qn = 0; qn < 2; ++qn)
                        #pragma unroll
                        for (int j = 0; j < NJQ; ++j) {
                            const int col = n0 + wc * WN + qn * HN + j * 16 + l15;
                            float v = acc[qm][qn][i][j][r];
                            if constexpr (EPI == 0) {
                                ((unsigned short*)Cv)[rbase + col] = f2b(v);
                            } else {
                                ((float*)Cv)[rbase + col] = v + ADD[rbase + col];
                            }
                        }
                }
    }
}

// ---------------- Dual-B GLU GEMM (R10 verified) ----------------
__global__ __launch_bounds__(512, 2) void gemm_glu(
    const unsigned short* __restrict__ A,
    const unsigned short* __restrict__ Bg,
    const unsigned short* __restrict__ By,
    unsigned short* __restrict__ act,
    int N, int K)
{
    constexpr int ABUF = 256 * 64, BBUF = 128 * 64;
    __shared__ __align__(16) unsigned short As[2 * ABUF];
    __shared__ __align__(16) unsigned short Bgs[2 * BBUF];
    __shared__ __align__(16) unsigned short Bys[2 * BBUF];

    const int t = threadIdx.x;
    const int l = t & 63, w = t >> 6;
    const int l15 = l & 15, lg = l >> 4;
    const int wr = w >> 2, wc = w & 3;
    const int x7 = l15 & 7;
    const int cc0 = ((lg) ^ x7) << 3;
    const int cc1 = ((4 | lg) ^ x7) << 3;

    const int nwg = (int)gridDim.x;
    const int orig = (int)blockIdx.x;
    const int q8 = nwg >> 3;
    const int xcd = orig & 7, lid = orig >> 3;
    const int wg = xcd * q8 + lid;
    const int m0 = (wg & 15) * 256;
    const int n0 = (wg >> 4) * 128;

    const int tr = t >> 3;
    const int scol = ((t & 7) ^ (tr & 7)) << 3;
    const unsigned short* pA[4];
    #pragma unroll
    for (int u = 0; u < 4; ++u) {
        const int lrow = u * 64 + tr;
        const int g = ((lrow >> 6) & 1) * 128 + (lrow >> 7) * 64 + (lrow & 63);
        pA[u] = A + (size_t)(m0 + g) * K + scol;
    }
    const unsigned short *pG[2], *pY[2];
    #pragma unroll
    for (int u = 0; u < 2; ++u) {
        const int g = (tr >> 4) * 32 + u * 16 + (tr & 15);
        pG[u] = Bg + (size_t)(n0 + g) * K + scol;
        pY[u] = By + (size_t)(n0 + g) * K + scol;
    }

    f32x4 accG[2][2][4] = {};
    f32x4 accY[2][2][4] = {};
    s16x8 aF[4][2];
    s16x8 gF[2][2], yF[2][2];

    const int NT = K / 64;

    #pragma unroll
    for (int u = 0; u < 4; ++u) GLD_LDS16(pA[u], &As[u * 4096 + t * 8]);
    GLD_LDS16(pG[0], &Bgs[0 * 4096 + t * 8]);
    GLD_LDS16(pY[0], &Bys[0 * 4096 + t * 8]);
    GLD_LDS16(pG[1], &Bgs[1 * 4096 + t * 8]);
    GLD_LDS16(pY[1], &Bys[1 * 4096 + t * 8]);
    asm volatile("s_waitcnt vmcnt(0)" ::: "memory");
    __builtin_amdgcn_s_barrier();

    for (int kt = 0; kt < NT; ++kt) {
        const int rb  = (kt & 1) ? ABUF : 0;
        const int rbB = (kt & 1) ? BBUF : 0;
        const int wb  = ABUF - rb;
        const int wbB = BBUF - rbB;
        const int knext = (kt + 1 < NT ? kt + 1 : kt) * 64;

        // ---- phase 1: (M0,GY0); stage all A' ----
        #pragma unroll
        for (int i = 0; i < 4; ++i) {
            const int lr = wr * 64 + i * 16 + l15;
            aF[i][0] = *(const s16x8*)&As[rb + lr * 64 + cc0];
            aF[i][1] = *(const s16x8*)&As[rb + lr * 64 + cc1];
        }
        {
            const int lr = wc * 16 + l15;
            gF[0][0] = *(const s16x8*)&Bgs[rbB + lr * 64 + cc0];
            gF[0][1] = *(const s16x8*)&Bgs[rbB + lr * 64 + cc1];
            yF[0][0] = *(const s16x8*)&Bys[rbB + lr * 64 + cc0];
            yF[0][1] = *(const s16x8*)&Bys[rbB + lr * 64 + cc1];
        }
        #pragma unroll
        for (int u = 0; u < 4; ++u)
            GLD_LDS16(pA[u] + knext, &As[wb + u * 4096 + t * 8]);
        __builtin_amdgcn_s_setprio(1);
        #pragma unroll
        for (int kk = 0; kk < 2; ++kk)
            #pragma unroll
            for (int i = 0; i < 4; ++i) {
                accG[0][0][i] = mfma16(aF[i][kk], gF[0][kk], accG[0][0][i]);
                accY[0][0][i] = mfma16(aF[i][kk], yF[0][kk], accY[0][0][i]);
            }
        __builtin_amdgcn_s_setprio(0);

        // ---- phase 2: (M0,GY1); stage all G',Y' ----
        {
            const int lr = 64 + wc * 16 + l15;
            gF[1][0] = *(const s16x8*)&Bgs[rbB + lr * 64 + cc0];
            gF[1][1] = *(const s16x8*)&Bgs[rbB + lr * 64 + cc1];
            yF[1][0] = *(const s16x8*)&Bys[rbB + lr * 64 + cc0];
            yF[1][1] = *(const s16x8*)&Bys[rbB + lr * 64 + cc1];
        }
        GLD_LDS16(pG[0] + knext, &Bgs[wbB + 0 * 4096 + t * 8]);
        GLD_LDS16(pY[0] + knext, &Bys[wbB + 0 * 4096 + t * 8]);
        GLD_LDS16(pG[1] + knext, &Bgs[wbB + 1 * 4096 + t * 8]);
        GLD_LDS16(pY[1] + knext, &Bys[wbB + 1 * 4096 + t * 8]);
        __builtin_amdgcn_s_setprio(1);
        #pragma unroll
        for (int kk = 0; kk < 2; ++kk)
            #pragma unroll
            for (int i = 0; i < 4; ++i) {
                accG[0][1][i] = mfma16(aF[i][kk], gF[1][kk], accG[0][1][i]);
                accY[0][1][i] = mfma16(aF[i][kk], yF[1][kk], accY[0][1][i]);
            }
        __builtin_amdgcn_s_setprio(0);

        // ---- phase 3: (M1,GY0) ----
        #pragma unroll
        for (int i = 0; i < 4; ++i) {
            const int lr = 128 + wr * 64 + i * 16 + l15;
            aF[i][0] = *(const s16x8*)&As[rb + lr * 64 + cc0];
            aF[i][1] = *(const s16x8*)&As[rb + lr * 64 + cc1];
        }
        __builtin_amdgcn_s_setprio(1);
        #pragma unroll
        for (int kk = 0; kk < 2; ++kk)
            #pragma unroll
            for (int i = 0; i < 4; ++i) {
                accG[1][0][i] = mfma16(aF[i][kk], gF[0][kk], accG[1][0][i]);
                accY[1][0][i] = mfma16(aF[i][kk], yF[0][kk], accY[1][0][i]);
            }
        __builtin_amdgcn_s_setprio(0);

        // ---- phase 4: (M1,GY1) ----
        __builtin_amdgcn_s_setprio(1);
        #pragma unroll
        for (int kk = 0; kk < 2; ++kk)
            #pragma unroll
            for (int i = 0; i < 4; ++i) {
                accG[1][1][i] = mfma16(aF[i][kk], gF[1][kk], accG[1][1][i]);
                accY[1][1][i] = mfma16(aF[i][kk], yF[1][kk], accY[1][1][i]);
            }
        __builtin_amdgcn_s_setprio(0);

        asm volatile("s_waitcnt vmcnt(0)" ::: "memory");
        __builtin_amdgcn_s_barrier();
    }

    #pragma unroll
    for (int qm = 0; qm < 2; ++qm)
        #pragma unroll
        for (int i = 0; i < 4; ++i)
            #pragma unroll
            for (int r = 0; r < 4; ++r) {
                const int row = m0 + wr * 128 + qm * 64 + i * 16 + lg * 4 + r;
                const size_t rbase = (size_t)row * N;
                #pragma unroll
                for (int qn = 0; qn < 2; ++qn) {
                    const int col = n0 + wc * 32 + qn * 16 + l15;
                    float g = accG[qm][qn][i][r];
                    float y = accY[qm][qn][i][r];
                    float sg = g / (1.0f + expf(-g));
                    act[rbase + col] = f2b(sg * y);
                }
            }
}

// ---------------- RoPE table: [S][32] of (cos, sin) ----------------
__global__ void rope_tab_k(float2* __restrict__ tab) {
    int i = blockIdx.x * 256 + threadIdx.x;
    if (i >= 4096 * 32) return;
    int s = i >> 5, d = i & 31;
    float inv = exp2f(-(float)d * (13.287712379549449f / 32.0f));
    float fr = (float)s * inv;
    float sv, cv;
    sincosf(fr, &sv, &cv);
    tab[i] = make_float2(cv, sv);
}

// ---------------- Sliding-window attention, mask-specialized tiles (R13) ----------------
__global__ __launch_bounds__(256) void attn_swa(
    const unsigned short* __restrict__ qkv,
    unsigned short* __restrict__ out)
{
    constexpr int LDQ = 3072;
    const int qb = blockIdx.x;
    const int h = blockIdx.y;
    const int kvh = h >> 2;
    const int q0 = qb * 64;
    const int t = threadIdx.x, l = t & 63, w = t >> 6;
    const int l15 = l & 15, lg = l >> 4;

    __shared__ unsigned short Kl[64 * 64];
    __shared__ unsigned short Vt[64 * 72];
    __shared__ unsigned short Pl[4 * 16 * 72];

    s16x8 qf[2];
    {
        const unsigned short* qp = qkv + (size_t)(q0 + w * 16 + l15) * LDQ + h * 64 + lg * 8;
        qf[0] = *(const s16x8*)(qp);
        qf[1] = *(const s16x8*)(qp + 32);
    }
    float m_run[4] = {-1e30f, -1e30f, -1e30f, -1e30f};
    float l_run[4] = {0.f, 0.f, 0.f, 0.f};
    f32x4 o[4] = {};

    const float SC = 0.0625f * 1.4426950408889634f;

    auto do_tile = [&](const int ks, const int mode) {
        __syncthreads();
        {
            const unsigned short* kg = qkv + (size_t)(ks + (t >> 3)) * LDQ + 2048 + kvh * 64 + (t & 7) * 8;
            GLD_LDS16(kg, Kl + t * 8);
            GLD_LDS16(kg + (size_t)32 * LDQ, Kl + t * 8 + 2048);
        }
        {
            const unsigned short* vg = qkv + (size_t)(ks + l) * LDQ + 2560 + kvh * 64 + w * 16;
            s16x8 v0 = *(const s16x8*)vg;
            s16x8 v1 = *(const s16x8*)(vg + 8);
            #pragma unroll
            for (int j = 0; j < 8; ++j) Vt[(w * 16 + j) * 72 + l] = (unsigned short)v0[j];
            #pragma unroll
            for (int j = 0; j < 8; ++j) Vt[(w * 16 + 8 + j) * 72 + l] = (unsigned short)v1[j];
        }
        __syncthreads();

        f32x4 sf[4] = {};
        #pragma unroll
        for (int kf = 0; kf < 4; ++kf) {
            #pragma unroll
            for (int kk = 0; kk < 2; ++kk) {
                s16x8 kb = *(const s16x8*)(Kl + (kf * 16 + l15) * 64 + kk * 32 + lg * 8);
                sf[kf] = mfma16(qf[kk], kb, sf[kf]);
            }
        }

        float tmax[4];
        #pragma unroll
        for (int r = 0; r < 4; ++r) {
            float mx;
            if (mode == 0) {
                mx = fmaxf(fmaxf(sf[0][r], sf[1][r]), fmaxf(sf[2][r], sf[3][r]));
            } else {
                const int qrow = q0 + w * 16 + lg * 4 + r;
                mx = -1e30f;
                #pragma unroll
                for (int kf = 0; kf < 4; ++kf) {
                    const int key = ks + kf * 16 + l15;
                    const bool valid = (mode == 1) ? (qrow - key < 512) : (key <= qrow);
                    if (valid) mx = fmaxf(mx, sf[kf][r]);
                }
            }
            #pragma unroll
            for (int d2 = 1; d2 < 16; d2 <<= 1) mx = fmaxf(mx, __shfl_xor(mx, d2));
            tmax[r] = mx;
        }

        float alpha[4], rsum[4];
        #pragma unroll
        for (int r = 0; r < 4; ++r) {
            float mnew = fmaxf(m_run[r], tmax[r]);
            alpha[r] = exp2f((m_run[r] - mnew) * SC);
            m_run[r] = mnew;
            rsum[r] = 0.f;
        }

        unsigned short* Pw = Pl + w * (16 * 72);
        #pragma unroll
        for (int kf = 0; kf < 4; ++kf) {
            #pragma unroll
            for (int r = 0; r < 4; ++r) {
                float p;
                if (mode == 0) {
                    p = exp2f((sf[kf][r] - m_run[r]) * SC);
                } else {
                    const int qrow = q0 + w * 16 + lg * 4 + r;
                    const int key = ks + kf * 16 + l15;
                    const bool valid = (mode == 1) ? (qrow - key < 512) : (key <= qrow);
                    p = valid ? exp2f((sf[kf][r] - m_run[r]) * SC) : 0.f;
                }
                rsum[r] += p;
                Pw[(lg * 4 + r) * 72 + kf * 16 + l15] = f2b(p);
            }
        }
        #pragma unroll
        for (int r = 0; r < 4; ++r) {
            #pragma unroll
            for (int d2 = 1; d2 < 16; d2 <<= 1) rsum[r] += __shfl_xor(rsum[r], d2);
            l_run[r] = l_run[r] * alpha[r] + rsum[r];
        }
        #pragma unroll
        for (int hf = 0; hf < 4; ++hf)
            #pragma unroll
            for (int r = 0; r < 4; ++r) o[hf][r] *= alpha[r];

        asm volatile("s_waitcnt lgkmcnt(0)" ::: "memory");
        __builtin_amdgcn_sched_barrier(0);

        #pragma unroll
        for (int kk2 = 0; kk2 < 2; ++kk2) {
            s16x8 pa = *(const s16x8*)(Pw + l15 * 72 + kk2 * 32 + lg * 8);
            #pragma unroll
            for (int hf = 0; hf < 4; ++hf) {
                s16x8 vb = *(const s16x8*)(Vt + (hf * 16 + l15) * 72 + kk2 * 32 + lg * 8);
                o[hf] = mfma16(pa, vb, o[hf]);
            }
        }
    };

    if (qb >= 8) {
        do_tile((qb - 8) * 64, 1);
        for (int kt = qb - 7; kt < qb; ++kt) do_tile(kt * 64, 0);
    } else {
        for (int kt = 0; kt < qb; ++kt) do_tile(kt * 64, 0);
    }
    do_tile(qb * 64, 2);

    #pragma unroll
    for (int r = 0; r < 4; ++r) {
        int qrow = q0 + w * 16 + lg * 4 + r;
        float invl = 1.0f / l_run[r];
        unsigned short* orow = out + (size_t)qrow * 2048 + h * 64;
        #pragma unroll
        for (int hf = 0; hf < 4; ++hf)
            orow[hf * 16 + l15] = f2b(o[hf][r] * invl);
    }
}

extern "C" void kernel_launch(void* const* d_in, const int* in_sizes, int n_in,
                              void* d_out, int out_size, void* d_ws, size_t ws_size,
                              hipStream_t stream)
{
    const float* hidden = (const float*)d_in[0];
    const float* w_mix  = (const float*)d_in[1];
    const float* wq     = (const float*)d_in[2];
    const float* wk     = (const float*)d_in[3];
    const float* wv     = (const float*)d_in[4];
    const float* wo     = (const float*)d_in[5];
    const float* w_mlp  = (const float*)d_in[6];
    const float* wg     = (const float*)d_in[7];
    const float* wd     = (const float*)d_in[8];
    float* out = (float*)d_out;

    char* ws = (char*)d_ws;
    size_t off = 0;
    auto alloc = [&](size_t bytes) {
        char* p = ws + off;
        off += (bytes + 255) & ~(size_t)255;
        return p;
    };
    unsigned short* Wt   = (unsigned short*)alloc((size_t)11264 * 2048 * 2);
    unsigned short* xn   = (unsigned short*)alloc((size_t)4096 * 2048 * 2);
    unsigned short* qkv  = (unsigned short*)alloc((size_t)4096 * 3072 * 2);
    float2*         rtab = (float2*)alloc((size_t)4096 * 32 * 8);
    unsigned short* attn = (unsigned short*)alloc((size_t)4096 * 2048 * 2);
    float*          hbuf = (float*)alloc((size_t)4096 * 2048 * 4);
    unsigned short* act  = (unsigned short*)alloc((size_t)4096 * 5632 * 2);

    // 0. RoPE table
    rope_tab_k<<<(4096 * 32 + 255) / 256, 256, 0, stream>>>(rtab);

    // 1. x = rmsnorm(hidden) -> bf16
    rmsnorm_bf16<<<4096, 256, 0, stream>>>(hidden, w_mix, xn);

    // 2. W^T for q,k,v concatenated
    transpose_to_bf16<<<dim3(32, 32), 256, 0, stream>>>(wq, Wt, 2048, 2048);
    transpose_to_bf16<<<dim3(8, 32), 256, 0, stream>>>(wk, Wt + (size_t)2048 * 2048, 2048, 512);
    transpose_to_bf16<<<dim3(8, 32), 256, 0, stream>>>(wv, Wt + (size_t)2560 * 2048, 2048, 512);

    // 3. qkv = x @ [wq|wk|wv] with fused RoPE   (N=3072) 256x256 -> 192 blocks
    gemmq<256, 2><<<192, 512, 0, stream>>>(xn, Wt, qkv, nullptr, rtab, 3072, 2048);

    // 4. sliding-window attention (per-head, mask-specialized)
    attn_swa<<<dim3(64, 32), 256, 0, stream>>>(qkv, attn);

    // 5. h = hidden + attn @ wo   (N=2048) 256x128 -> 256 blocks
    transpose_to_bf16<<<dim3(32, 32), 256, 0, stream>>>(wo, Wt, 2048, 2048);
    gemmq<128, 1><<<256, 512, 0, stream>>>(attn, Wt, hbuf, hidden, nullptr, 2048, 2048);

    // 6. xn2 = rmsnorm(h)
    rmsnorm_bf16<<<4096, 256, 0, stream>>>(hbuf, w_mlp, xn);

    // 7. MLP: act = silu(x@wg_gate^T) * (x@wg_y^T)  -- 704 blocks
    transpose_to_bf16<<<dim3(176, 32), 256, 0, stream>>>(wg, Wt, 2048, 11264);
    gemm_glu<<<704, 512, 0, stream>>>(xn, Wt, Wt + (size_t)5632 * 2048, act, 5632, 2048);

    // 8. out = h + act @ w_down   (N=2048, K=5632) 256x128 -> 256 blocks
    transpose_to_bf16<<<dim3(32, 88), 256, 0, stream>>>(wd, Wt, 5632, 2048);
    gemmq<128, 1><<<256, 512, 0, stream>>>(act, Wt, out, hbuf, nullptr, 2048, 5632);
}

// Round 16
// 515.992 us; speedup vs baseline: 1.1196x; 1.0504x over previous
//
#include <hip/hip_runtime.h>
#include <stdint.h>

typedef __attribute__((ext_vector_type(8))) short s16x8;
typedef __attribute__((ext_vector_type(4))) float f32x4;
typedef __attribute__((ext_vector_type(4))) unsigned short u16x4;

#define GLD_LDS16(gp, lp) __builtin_amdgcn_global_load_lds( \
    (__attribute__((address_space(1))) void*)(void*)(gp), \
    (__attribute__((address_space(3))) void*)(lp), 16, 0, 0)

__device__ __forceinline__ float b2f(unsigned short s) {
    unsigned int u = ((unsigned int)s) << 16;
    return __builtin_bit_cast(float, u);
}
__device__ __forceinline__ unsigned short f2b(float f) {
    unsigned int u = __builtin_bit_cast(unsigned int, f);
    u = (u + 0x7FFFu + ((u >> 16) & 1u)) >> 16;
    return (unsigned short)u;
}
__device__ __forceinline__ f32x4 mfma16(s16x8 a, s16x8 b, f32x4 c) {
    return __builtin_amdgcn_mfma_f32_16x16x32_bf16(a, b, c, 0, 0, 0);
}

// ---------------- RMSNorm (fp32 in -> bf16 out), D = 2048 ----------------
__global__ __launch_bounds__(256) void rmsnorm_bf16(
    const float* __restrict__ x, const float* __restrict__ wgt,
    unsigned short* __restrict__ out)
{
    const int row = blockIdx.x;
    const int t = threadIdx.x;
    const float* xr = x + (size_t)row * 2048;
    float4 a = *(const float4*)(xr + t * 8);
    float4 b = *(const float4*)(xr + t * 8 + 4);
    float ss = a.x*a.x + a.y*a.y + a.z*a.z + a.w*a.w
             + b.x*b.x + b.y*b.y + b.z*b.z + b.w*b.w;
    #pragma unroll
    for (int d = 1; d < 64; d <<= 1) ss += __shfl_xor(ss, d);
    __shared__ float red[4];
    if ((t & 63) == 0) red[t >> 6] = ss;
    __syncthreads();
    float tot = red[0] + red[1] + red[2] + red[3];
    float inv = rsqrtf(tot * (1.0f / 2048.0f) + 1e-5f);
    float vals[8] = {a.x, a.y, a.z, a.w, b.x, b.y, b.z, b.w};
    const float* wr_ = wgt + t * 8;
    s16x8 ov;
    #pragma unroll
    for (int j = 0; j < 8; ++j) ov[j] = (short)f2b(vals[j] * inv * wr_[j]);
    *(s16x8*)(out + (size_t)row * 2048 + t * 8) = ov;
}

// ------------- transpose + convert: in fp32 [K][N] -> out bf16 [N][K] -------------
__global__ __launch_bounds__(256) void transpose_to_bf16(
    const float* __restrict__ in, unsigned short* __restrict__ out, int K, int N)
{
    __shared__ float tile[64][65];
    const int n0 = blockIdx.x * 64, k0 = blockIdx.y * 64;
    const int t = threadIdx.x;
    const int kr = t >> 4, nc = (t & 15) * 4;
    #pragma unroll
    for (int i = 0; i < 4; ++i) {
        float4 v = *(const float4*)(in + (size_t)(k0 + kr + i * 16) * N + n0 + nc);
        tile[nc + 0][kr + i * 16] = v.x;
        tile[nc + 1][kr + i * 16] = v.y;
        tile[nc + 2][kr + i * 16] = v.z;
        tile[nc + 3][kr + i * 16] = v.w;
    }
    __syncthreads();
    const int nr = t >> 3, kc = (t & 7) * 8;
    #pragma unroll
    for (int p = 0; p < 2; ++p) {
        s16x8 o;
        #pragma unroll
        for (int j = 0; j < 8; ++j) o[j] = (short)f2b(tile[nr + p * 32][kc + j]);
        *(s16x8*)(out + (size_t)(n0 + nr + p * 32) * K + k0 + kc) = o;
    }
}

// ---------------- Minimal-sync GEMM (R10 verified: 48% MfmaUtil) ----------------
template <int BN, int EPI>
__global__ __launch_bounds__(512, 2) void gemmq(
    const unsigned short* __restrict__ A,
    const unsigned short* __restrict__ B,
    void* __restrict__ Cv,
    const float* __restrict__ ADD,
    const float2* __restrict__ RT,
    int N, int K)
{
    constexpr int WN  = BN / 4;
    constexpr int HN  = WN / 2;
    constexpr int NJQ = WN / 32;
    constexpr int NBU = BN / 64;
    constexpr int ABUF = 256 * 64;
    constexpr int BBUF = BN * 64;
    __shared__ __align__(16) unsigned short As[2 * ABUF];
    __shared__ __align__(16) unsigned short Bs[2 * BBUF];

    const int t = threadIdx.x;
    const int l = t & 63, w = t >> 6;
    const int l15 = l & 15, lg = l >> 4;
    const int wr = w >> 2, wc = w & 3;
    const int x7 = l15 & 7;
    const int cc0 = ((lg) ^ x7) << 3;
    const int cc1 = ((4 | lg) ^ x7) << 3;

    const int nwg = (int)gridDim.x;
    const int orig = (int)blockIdx.x;
    const int q8 = nwg >> 3, r8 = nwg & 7;
    const int xcd = orig & 7, lid = orig >> 3;
    const int wg = (xcd < r8 ? xcd * (q8 + 1) : r8 * (q8 + 1) + (xcd - r8) * q8) + lid;
    const int m0 = (wg & 15) * 256;
    const int n0 = (wg >> 4) * BN;

    const int tr = t >> 3;
    const int scol = ((t & 7) ^ (tr & 7)) << 3;
    const unsigned short* pA[4];
    #pragma unroll
    for (int u = 0; u < 4; ++u) {
        const int lrow = u * 64 + tr;
        const int g = ((lrow >> 6) & 1) * 128 + (lrow >> 7) * 64 + (lrow & 63);
        pA[u] = A + (size_t)(m0 + g) * K + scol;
    }
    const unsigned short* pB[NBU];
    #pragma unroll
    for (int u = 0; u < NBU; ++u) {
        const int lrow = u * 64 + tr;
        const int h = lrow / (BN / 2), rem = lrow % (BN / 2);
        const int g = (rem / HN) * WN + h * HN + (rem % HN);
        pB[u] = B + (size_t)(n0 + g) * K + scol;
    }

    f32x4 acc[2][2][4][NJQ] = {};
    s16x8 aF[4][2];
    s16x8 bF[2][NJQ][2];

    const int NT = K / 64;

    #pragma unroll
    for (int u = 0; u < 4; ++u) GLD_LDS16(pA[u], &As[u * 4096 + t * 8]);
    #pragma unroll
    for (int u = 0; u < NBU; ++u) GLD_LDS16(pB[u], &Bs[u * 4096 + t * 8]);
    asm volatile("s_waitcnt vmcnt(0)" ::: "memory");
    __builtin_amdgcn_s_barrier();

    for (int kt = 0; kt < NT; ++kt) {
        const int rb  = (kt & 1) ? ABUF : 0;
        const int rbB = (kt & 1) ? BBUF : 0;
        const int wb  = ABUF - rb;
        const int wbB = BBUF - rbB;
        const int knext = (kt + 1 < NT ? kt + 1 : kt) * 64;

        // ---- phase 1: (M0,N0); stage all A' ----
        #pragma unroll
        for (int i = 0; i < 4; ++i) {
            const int lr = wr * 64 + i * 16 + l15;
            aF[i][0] = *(const s16x8*)&As[rb + lr * 64 + cc0];
            aF[i][1] = *(const s16x8*)&As[rb + lr * 64 + cc1];
        }
        #pragma unroll
        for (int j = 0; j < NJQ; ++j) {
            const int lr = wc * HN + j * 16 + l15;
            bF[0][j][0] = *(const s16x8*)&Bs[rbB + lr * 64 + cc0];
            bF[0][j][1] = *(const s16x8*)&Bs[rbB + lr * 64 + cc1];
        }
        #pragma unroll
        for (int u = 0; u < 4; ++u)
            GLD_LDS16(pA[u] + knext, &As[wb + u * 4096 + t * 8]);
        __builtin_amdgcn_s_setprio(1);
        #pragma unroll
        for (int kk = 0; kk < 2; ++kk)
            #pragma unroll
            for (int i = 0; i < 4; ++i)
                #pragma unroll
                for (int j = 0; j < NJQ; ++j)
                    acc[0][0][i][j] = mfma16(aF[i][kk], bF[0][j][kk], acc[0][0][i][j]);
        __builtin_amdgcn_s_setprio(0);

        // ---- phase 2: (M0,N1); stage all B' ----
        #pragma unroll
        for (int j = 0; j < NJQ; ++j) {
            const int lr = (BN / 2) + wc * HN + j * 16 + l15;
            bF[1][j][0] = *(const s16x8*)&Bs[rbB + lr * 64 + cc0];
            bF[1][j][1] = *(const s16x8*)&Bs[rbB + lr * 64 + cc1];
        }
        #pragma unroll
        for (int u = 0; u < NBU; ++u)
            GLD_LDS16(pB[u] + knext, &Bs[wbB + u * 4096 + t * 8]);
        __builtin_amdgcn_s_setprio(1);
        #pragma unroll
        for (int kk = 0; kk < 2; ++kk)
            #pragma unroll
            for (int i = 0; i < 4; ++i)
                #pragma unroll
                for (int j = 0; j < NJQ; ++j)
                    acc[0][1][i][j] = mfma16(aF[i][kk], bF[1][j][kk], acc[0][1][i][j]);
        __builtin_amdgcn_s_setprio(0);

        // ---- phase 3: (M1,N0) ----
        #pragma unroll
        for (int i = 0; i < 4; ++i) {
            const int lr = 128 + wr * 64 + i * 16 + l15;
            aF[i][0] = *(const s16x8*)&As[rb + lr * 64 + cc0];
            aF[i][1] = *(const s16x8*)&As[rb + lr * 64 + cc1];
        }
        __builtin_amdgcn_s_setprio(1);
        #pragma unroll
        for (int kk = 0; kk < 2; ++kk)
            #pragma unroll
            for (int i = 0; i < 4; ++i)
                #pragma unroll
                for (int j = 0; j < NJQ; ++j)
                    acc[1][0][i][j] = mfma16(aF[i][kk], bF[0][j][kk], acc[1][0][i][j]);
        __builtin_amdgcn_s_setprio(0);

        // ---- phase 4: (M1,N1) ----
        __builtin_amdgcn_s_setprio(1);
        #pragma unroll
        for (int kk = 0; kk < 2; ++kk)
            #pragma unroll
            for (int i = 0; i < 4; ++i)
                #pragma unroll
                for (int j = 0; j < NJQ; ++j)
                    acc[1][1][i][j] = mfma16(aF[i][kk], bF[1][j][kk], acc[1][1][i][j]);
        __builtin_amdgcn_s_setprio(0);

        asm volatile("s_waitcnt vmcnt(0)" ::: "memory");
        __builtin_amdgcn_s_barrier();
    }

    if constexpr (EPI == 2) {
        unsigned short* Cb = (unsigned short*)Cv;
        const bool roped = (n0 < 2560);
        #pragma unroll
        for (int qm = 0; qm < 2; ++qm)
            #pragma unroll
            for (int i = 0; i < 4; ++i)
                #pragma unroll
                for (int r = 0; r < 4; ++r) {
                    const int row = m0 + wr * 128 + qm * 64 + i * 16 + lg * 4 + r;
                    const size_t rbase = (size_t)row * N;
                    #pragma unroll
                    for (int j = 0; j < NJQ; ++j) {
                        const int d = j * 16 + l15;
                        const int c0 = n0 + wc * WN + j * 16 + l15;
                        float a = acc[qm][0][i][j][r];
                        float b = acc[qm][1][i][j][r];
                        if (roped) {
                            float2 cs = RT[row * 32 + d];
                            Cb[rbase + c0]      = f2b(a * cs.x - b * cs.y);
                            Cb[rbase + c0 + HN] = f2b(b * cs.x + a * cs.y);
                        } else {
                            Cb[rbase + c0]      = f2b(a);
                            Cb[rbase + c0 + HN] = f2b(b);
                        }
                    }
                }
    } else {
        #pragma unroll
        for (int qm = 0; qm < 2; ++qm)
            #pragma unroll
            for (int i = 0; i < 4; ++i)
                #pragma unroll
                for (int r = 0; r < 4; ++r) {
                    const int row = m0 + wr * 128 + qm * 64 + i * 16 + lg * 4 + r;
                    const size_t rbase = (size_t)row * N;
                    #pragma unroll
                    for (int qn = 0; qn < 2; ++qn)
                        #pragma unroll
                        for (int j = 0; j < NJQ; ++j) {
                            const int col = n0 + wc * WN + qn * HN + j * 16 + l15;
                            float v = acc[qm][qn][i][j][r];
                            if constexpr (EPI == 0) {
                                ((unsigned short*)Cv)[rbase + col] = f2b(v);
                            } else {
                                ((float*)Cv)[rbase + col] = v + ADD[rbase + col];
                            }
                        }
                }
    }
}

// ---------------- Dual-B GLU GEMM (R10 verified) ----------------
__global__ __launch_bounds__(512, 2) void gemm_glu(
    const unsigned short* __restrict__ A,
    const unsigned short* __restrict__ Bg,
    const unsigned short* __restrict__ By,
    unsigned short* __restrict__ act,
    int N, int K)
{
    constexpr int ABUF = 256 * 64, BBUF = 128 * 64;
    __shared__ __align__(16) unsigned short As[2 * ABUF];
    __shared__ __align__(16) unsigned short Bgs[2 * BBUF];
    __shared__ __align__(16) unsigned short Bys[2 * BBUF];

    const int t = threadIdx.x;
    const int l = t & 63, w = t >> 6;
    const int l15 = l & 15, lg = l >> 4;
    const int wr = w >> 2, wc = w & 3;
    const int x7 = l15 & 7;
    const int cc0 = ((lg) ^ x7) << 3;
    const int cc1 = ((4 | lg) ^ x7) << 3;

    const int nwg = (int)gridDim.x;
    const int orig = (int)blockIdx.x;
    const int q8 = nwg >> 3;
    const int xcd = orig & 7, lid = orig >> 3;
    const int wg = xcd * q8 + lid;
    const int m0 = (wg & 15) * 256;
    const int n0 = (wg >> 4) * 128;

    const int tr = t >> 3;
    const int scol = ((t & 7) ^ (tr & 7)) << 3;
    const unsigned short* pA[4];
    #pragma unroll
    for (int u = 0; u < 4; ++u) {
        const int lrow = u * 64 + tr;
        const int g = ((lrow >> 6) & 1) * 128 + (lrow >> 7) * 64 + (lrow & 63);
        pA[u] = A + (size_t)(m0 + g) * K + scol;
    }
    const unsigned short *pG[2], *pY[2];
    #pragma unroll
    for (int u = 0; u < 2; ++u) {
        const int g = (tr >> 4) * 32 + u * 16 + (tr & 15);
        pG[u] = Bg + (size_t)(n0 + g) * K + scol;
        pY[u] = By + (size_t)(n0 + g) * K + scol;
    }

    f32x4 accG[2][2][4] = {};
    f32x4 accY[2][2][4] = {};
    s16x8 aF[4][2];
    s16x8 gF[2][2], yF[2][2];

    const int NT = K / 64;

    #pragma unroll
    for (int u = 0; u < 4; ++u) GLD_LDS16(pA[u], &As[u * 4096 + t * 8]);
    GLD_LDS16(pG[0], &Bgs[0 * 4096 + t * 8]);
    GLD_LDS16(pY[0], &Bys[0 * 4096 + t * 8]);
    GLD_LDS16(pG[1], &Bgs[1 * 4096 + t * 8]);
    GLD_LDS16(pY[1], &Bys[1 * 4096 + t * 8]);
    asm volatile("s_waitcnt vmcnt(0)" ::: "memory");
    __builtin_amdgcn_s_barrier();

    for (int kt = 0; kt < NT; ++kt) {
        const int rb  = (kt & 1) ? ABUF : 0;
        const int rbB = (kt & 1) ? BBUF : 0;
        const int wb  = ABUF - rb;
        const int wbB = BBUF - rbB;
        const int knext = (kt + 1 < NT ? kt + 1 : kt) * 64;

        // ---- phase 1: (M0,GY0); stage all A' ----
        #pragma unroll
        for (int i = 0; i < 4; ++i) {
            const int lr = wr * 64 + i * 16 + l15;
            aF[i][0] = *(const s16x8*)&As[rb + lr * 64 + cc0];
            aF[i][1] = *(const s16x8*)&As[rb + lr * 64 + cc1];
        }
        {
            const int lr = wc * 16 + l15;
            gF[0][0] = *(const s16x8*)&Bgs[rbB + lr * 64 + cc0];
            gF[0][1] = *(const s16x8*)&Bgs[rbB + lr * 64 + cc1];
            yF[0][0] = *(const s16x8*)&Bys[rbB + lr * 64 + cc0];
            yF[0][1] = *(const s16x8*)&Bys[rbB + lr * 64 + cc1];
        }
        #pragma unroll
        for (int u = 0; u < 4; ++u)
            GLD_LDS16(pA[u] + knext, &As[wb + u * 4096 + t * 8]);
        __builtin_amdgcn_s_setprio(1);
        #pragma unroll
        for (int kk = 0; kk < 2; ++kk)
            #pragma unroll
            for (int i = 0; i < 4; ++i) {
                accG[0][0][i] = mfma16(aF[i][kk], gF[0][kk], accG[0][0][i]);
                accY[0][0][i] = mfma16(aF[i][kk], yF[0][kk], accY[0][0][i]);
            }
        __builtin_amdgcn_s_setprio(0);

        // ---- phase 2: (M0,GY1); stage all G',Y' ----
        {
            const int lr = 64 + wc * 16 + l15;
            gF[1][0] = *(const s16x8*)&Bgs[rbB + lr * 64 + cc0];
            gF[1][1] = *(const s16x8*)&Bgs[rbB + lr * 64 + cc1];
            yF[1][0] = *(const s16x8*)&Bys[rbB + lr * 64 + cc0];
            yF[1][1] = *(const s16x8*)&Bys[rbB + lr * 64 + cc1];
        }
        GLD_LDS16(pG[0] + knext, &Bgs[wbB + 0 * 4096 + t * 8]);
        GLD_LDS16(pY[0] + knext, &Bys[wbB + 0 * 4096 + t * 8]);
        GLD_LDS16(pG[1] + knext, &Bgs[wbB + 1 * 4096 + t * 8]);
        GLD_LDS16(pY[1] + knext, &Bys[wbB + 1 * 4096 + t * 8]);
        __builtin_amdgcn_s_setprio(1);
        #pragma unroll
        for (int kk = 0; kk < 2; ++kk)
            #pragma unroll
            for (int i = 0; i < 4; ++i) {
                accG[0][1][i] = mfma16(aF[i][kk], gF[1][kk], accG[0][1][i]);
                accY[0][1][i] = mfma16(aF[i][kk], yF[1][kk], accY[0][1][i]);
            }
        __builtin_amdgcn_s_setprio(0);

        // ---- phase 3: (M1,GY0) ----
        #pragma unroll
        for (int i = 0; i < 4; ++i) {
            const int lr = 128 + wr * 64 + i * 16 + l15;
            aF[i][0] = *(const s16x8*)&As[rb + lr * 64 + cc0];
            aF[i][1] = *(const s16x8*)&As[rb + lr * 64 + cc1];
        }
        __builtin_amdgcn_s_setprio(1);
        #pragma unroll
        for (int kk = 0; kk < 2; ++kk)
            #pragma unroll
            for (int i = 0; i < 4; ++i) {
                accG[1][0][i] = mfma16(aF[i][kk], gF[0][kk], accG[1][0][i]);
                accY[1][0][i] = mfma16(aF[i][kk], yF[0][kk], accY[1][0][i]);
            }
        __builtin_amdgcn_s_setprio(0);

        // ---- phase 4: (M1,GY1) ----
        __builtin_amdgcn_s_setprio(1);
        #pragma unroll
        for (int kk = 0; kk < 2; ++kk)
            #pragma unroll
            for (int i = 0; i < 4; ++i) {
                accG[1][1][i] = mfma16(aF[i][kk], gF[1][kk], accG[1][1][i]);
                accY[1][1][i] = mfma16(aF[i][kk], yF[1][kk], accY[1][1][i]);
            }
        __builtin_amdgcn_s_setprio(0);

        asm volatile("s_waitcnt vmcnt(0)" ::: "memory");
        __builtin_amdgcn_s_barrier();
    }

    #pragma unroll
    for (int qm = 0; qm < 2; ++qm)
        #pragma unroll
        for (int i = 0; i < 4; ++i)
            #pragma unroll
            for (int r = 0; r < 4; ++r) {
                const int row = m0 + wr * 128 + qm * 64 + i * 16 + lg * 4 + r;
                const size_t rbase = (size_t)row * N;
                #pragma unroll
                for (int qn = 0; qn < 2; ++qn) {
                    const int col = n0 + wc * 32 + qn * 16 + l15;
                    float g = accG[qm][qn][i][r];
                    float y = accY[qm][qn][i][r];
                    float sg = g / (1.0f + expf(-g));
                    act[rbase + col] = f2b(sg * y);
                }
            }
}

// ---------------- RoPE table: [S][32] of (cos, sin) ----------------
__global__ void rope_tab_k(float2* __restrict__ tab) {
    int i = blockIdx.x * 256 + threadIdx.x;
    if (i >= 4096 * 32) return;
    int s = i >> 5, d = i & 31;
    float inv = exp2f(-(float)d * (13.287712379549449f / 32.0f));
    float fr = (float)s * inv;
    float sv, cv;
    sincosf(fr, &sv, &cv);
    tab[i] = make_float2(cv, sv);
}

// ---------------- Sliding-window attention: swapped-QK^T, lane-local softmax ----------------
// S^T = mfma(K, Q): lane (l15,lg) holds scores for q = q0+w*16+l15 at keys
// kf*16+lg*4+r. Row-softmax: 16 in-lane values + 2 shuffles (xor 16,32).
// P-write: 4 consecutive keys -> one b64 store. alpha/invl broadcast via shfl
// to the o-accumulator rows (q = lg*4+r). PV and P layout [q][key] unchanged.
// Mask-specialized tiles (R13): interior tiles unmasked.
__global__ __launch_bounds__(256) void attn_swa(
    const unsigned short* __restrict__ qkv,
    unsigned short* __restrict__ out)
{
    constexpr int LDQ = 3072;
    const int qb = blockIdx.x;
    const int h = blockIdx.y;
    const int kvh = h >> 2;
    const int q0 = qb * 64;
    const int t = threadIdx.x, l = t & 63, w = t >> 6;
    const int l15 = l & 15, lg = l >> 4;

    __shared__ unsigned short Kl[64 * 64];
    __shared__ unsigned short Vt[64 * 72];
    __shared__ unsigned short Pl[4 * 16 * 72];

    s16x8 qf[2];
    {
        const unsigned short* qp = qkv + (size_t)(q0 + w * 16 + l15) * LDQ + h * 64 + lg * 8;
        qf[0] = *(const s16x8*)(qp);
        qf[1] = *(const s16x8*)(qp + 32);
    }
    const int myq = q0 + w * 16 + l15;     // q owned by this lane's softmax state
    float m_run = -1e30f;
    float l_run = 0.f;
    f32x4 o[4] = {};

    const float SC = 0.0625f * 1.4426950408889634f;

    auto do_tile = [&](const int ks, const int mode) {
        __syncthreads();
        {
            const unsigned short* kg = qkv + (size_t)(ks + (t >> 3)) * LDQ + 2048 + kvh * 64 + (t & 7) * 8;
            GLD_LDS16(kg, Kl + t * 8);
            GLD_LDS16(kg + (size_t)32 * LDQ, Kl + t * 8 + 2048);
        }
        {
            const unsigned short* vg = qkv + (size_t)(ks + l) * LDQ + 2560 + kvh * 64 + w * 16;
            s16x8 v0 = *(const s16x8*)vg;
            s16x8 v1 = *(const s16x8*)(vg + 8);
            #pragma unroll
            for (int j = 0; j < 8; ++j) Vt[(w * 16 + j) * 72 + l] = (unsigned short)v0[j];
            #pragma unroll
            for (int j = 0; j < 8; ++j) Vt[(w * 16 + 8 + j) * 72 + l] = (unsigned short)v1[j];
        }
        __syncthreads();

        // S^T: sf[kf][r] = S[key = ks + kf*16 + lg*4 + r][q = myq]
        f32x4 sf[4] = {};
        #pragma unroll
        for (int kf = 0; kf < 4; ++kf) {
            #pragma unroll
            for (int kk = 0; kk < 2; ++kk) {
                s16x8 kb = *(const s16x8*)(Kl + (kf * 16 + l15) * 64 + kk * 32 + lg * 8);
                sf[kf] = mfma16(kb, qf[kk], sf[kf]);   // swapped operands
            }
        }

        // masked in-lane max + 2-shuffle reduce (keys split across lg groups)
        float mx = -1e30f;
        if (mode == 0) {
            #pragma unroll
            for (int kf = 0; kf < 4; ++kf) {
                float a = fmaxf(sf[kf][0], sf[kf][1]);
                float b = fmaxf(sf[kf][2], sf[kf][3]);
                mx = fmaxf(mx, fmaxf(a, b));
            }
        } else {
            #pragma unroll
            for (int kf = 0; kf < 4; ++kf)
                #pragma unroll
                for (int r = 0; r < 4; ++r) {
                    const int key = ks + kf * 16 + lg * 4 + r;
                    const bool valid = (mode == 1) ? (myq - key < 512) : (key <= myq);
                    if (valid) mx = fmaxf(mx, sf[kf][r]);
                }
        }
        mx = fmaxf(mx, __shfl_xor(mx, 16));
        mx = fmaxf(mx, __shfl_xor(mx, 32));

        const float mnew = fmaxf(m_run, mx);
        const float alpha_s = exp2f((m_run - mnew) * SC);
        m_run = mnew;

        unsigned short* Pw = Pl + w * (16 * 72);
        float rs = 0.f;
        #pragma unroll
        for (int kf = 0; kf < 4; ++kf) {
            u16x4 pk;
            #pragma unroll
            for (int r = 0; r < 4; ++r) {
                float p;
                if (mode == 0) {
                    p = exp2f((sf[kf][r] - mnew) * SC);
                } else {
                    const int key = ks + kf * 16 + lg * 4 + r;
                    const bool valid = (mode == 1) ? (myq - key < 512) : (key <= myq);
                    p = valid ? exp2f((sf[kf][r] - mnew) * SC) : 0.f;
                }
                rs += p;
                pk[r] = f2b(p);
            }
            *(u16x4*)(Pw + l15 * 72 + kf * 16 + lg * 4) = pk;   // 8-B aligned b64 store
        }
        rs += __shfl_xor(rs, 16);
        rs += __shfl_xor(rs, 32);
        l_run = l_run * alpha_s + rs;

        // broadcast alpha to o rows: row r holds q = q0+w*16+lg*4+r
        #pragma unroll
        for (int r = 0; r < 4; ++r) {
            const float ar = __shfl(alpha_s, (lg << 4) | (lg * 4 + r));
            #pragma unroll
            for (int hf = 0; hf < 4; ++hf) o[hf][r] *= ar;
        }

        asm volatile("s_waitcnt lgkmcnt(0)" ::: "memory");
        __builtin_amdgcn_sched_barrier(0);

        #pragma unroll
        for (int kk2 = 0; kk2 < 2; ++kk2) {
            s16x8 pa = *(const s16x8*)(Pw + l15 * 72 + kk2 * 32 + lg * 8);
            #pragma unroll
            for (int hf = 0; hf < 4; ++hf) {
                s16x8 vb = *(const s16x8*)(Vt + (hf * 16 + l15) * 72 + kk2 * 32 + lg * 8);
                o[hf] = mfma16(pa, vb, o[hf]);
            }
        }
    };

    if (qb >= 8) {
        do_tile((qb - 8) * 64, 1);
        for (int kt = qb - 7; kt < qb; ++kt) do_tile(kt * 64, 0);
    } else {
        for (int kt = 0; kt < qb; ++kt) do_tile(kt * 64, 0);
    }
    do_tile(qb * 64, 2);

    const float invl_s = 1.0f / l_run;
    #pragma unroll
    for (int r = 0; r < 4; ++r) {
        const float ir = __shfl(invl_s, (lg << 4) | (lg * 4 + r));
        const int qrow = q0 + w * 16 + lg * 4 + r;
        unsigned short* orow = out + (size_t)qrow * 2048 + h * 64;
        #pragma unroll
        for (int hf = 0; hf < 4; ++hf)
            orow[hf * 16 + l15] = f2b(o[hf][r] * ir);
    }
}

extern "C" void kernel_launch(void* const* d_in, const int* in_sizes, int n_in,
                              void* d_out, int out_size, void* d_ws, size_t ws_size,
                              hipStream_t stream)
{
    const float* hidden = (const float*)d_in[0];
    const float* w_mix  = (const float*)d_in[1];
    const float* wq     = (const float*)d_in[2];
    const float* wk     = (const float*)d_in[3];
    const float* wv     = (const float*)d_in[4];
    const float* wo     = (const float*)d_in[5];
    const float* w_mlp  = (const float*)d_in[6];
    const float* wg     = (const float*)d_in[7];
    const float* wd     = (const float*)d_in[8];
    float* out = (float*)d_out;

    char* ws = (char*)d_ws;
    size_t off = 0;
    auto alloc = [&](size_t bytes) {
        char* p = ws + off;
        off += (bytes + 255) & ~(size_t)255;
        return p;
    };
    unsigned short* Wt   = (unsigned short*)alloc((size_t)11264 * 2048 * 2);
    unsigned short* xn   = (unsigned short*)alloc((size_t)4096 * 2048 * 2);
    unsigned short* qkv  = (unsigned short*)alloc((size_t)4096 * 3072 * 2);
    float2*         rtab = (float2*)alloc((size_t)4096 * 32 * 8);
    unsigned short* attn = (unsigned short*)alloc((size_t)4096 * 2048 * 2);
    float*          hbuf = (float*)alloc((size_t)4096 * 2048 * 4);
    unsigned short* act  = (unsigned short*)alloc((size_t)4096 * 5632 * 2);

    // 0. RoPE table
    rope_tab_k<<<(4096 * 32 + 255) / 256, 256, 0, stream>>>(rtab);

    // 1. x = rmsnorm(hidden) -> bf16
    rmsnorm_bf16<<<4096, 256, 0, stream>>>(hidden, w_mix, xn);

    // 2. W^T for q,k,v concatenated
    transpose_to_bf16<<<dim3(32, 32), 256, 0, stream>>>(wq, Wt, 2048, 2048);
    transpose_to_bf16<<<dim3(8, 32), 256, 0, stream>>>(wk, Wt + (size_t)2048 * 2048, 2048, 512);
    transpose_to_bf16<<<dim3(8, 32), 256, 0, stream>>>(wv, Wt + (size_t)2560 * 2048, 2048, 512);

    // 3. qkv = x @ [wq|wk|wv] with fused RoPE   (N=3072) 256x256 -> 192 blocks
    gemmq<256, 2><<<192, 512, 0, stream>>>(xn, Wt, qkv, nullptr, rtab, 3072, 2048);

    // 4. sliding-window attention (swapped-QK, lane-local softmax)
    attn_swa<<<dim3(64, 32), 256, 0, stream>>>(qkv, attn);

    // 5. h = hidden + attn @ wo   (N=2048) 256x128 -> 256 blocks
    transpose_to_bf16<<<dim3(32, 32), 256, 0, stream>>>(wo, Wt, 2048, 2048);
    gemmq<128, 1><<<256, 512, 0, stream>>>(attn, Wt, hbuf, hidden, nullptr, 2048, 2048);

    // 6. xn2 = rmsnorm(h)
    rmsnorm_bf16<<<4096, 256, 0, stream>>>(hbuf, w_mlp, xn);

    // 7. MLP: act = silu(x@wg_gate^T) * (x@wg_y^T)  -- 704 blocks
    transpose_to_bf16<<<dim3(176, 32), 256, 0, stream>>>(wg, Wt, 2048, 11264);
    gemm_glu<<<704, 512, 0, stream>>>(xn, Wt, Wt + (size_t)5632 * 2048, act, 5632, 2048);

    // 8. out = h + act @ w_down   (N=2048, K=5632) 256x128 -> 256 blocks
    transpose_to_bf16<<<dim3(32, 88), 256, 0, stream>>>(wd, Wt, 5632, 2048);
    gemmq<128, 1><<<256, 512, 0, stream>>>(act, Wt, out, hbuf, nullptr, 2048, 5632);
}